// Round 6
// baseline (555.262 us; speedup 1.0000x reference)
//
#include <hip/hip_runtime.h>
#include <cstddef>

#define NN 100000
#define NE 1600000

typedef unsigned int uint;
typedef unsigned short ushort;
typedef short bf16x8 __attribute__((ext_vector_type(8)));
typedef float f32x16 __attribute__((ext_vector_type(16)));

__device__ inline uint bf16_rne(float f) {   // fp32 -> bf16 bits (round-nearest-even)
  uint u = __float_as_uint(f);
  u += 0x7fffu + ((u >> 16) & 1u);
  return u >> 16;
}
__device__ inline float blo(uint u) { return __uint_as_float(u << 16); }
__device__ inline float bhi(uint u) { return __uint_as_float(u & 0xffff0000u); }

// ---------------- degree count ----------------
__global__ void __launch_bounds__(256) k_count(const int* __restrict__ dst,
                                               uint* __restrict__ cnt, int E) {
  int i = blockIdx.x * 256 + threadIdx.x;
  if (i < E) atomicAdd(&cnt[dst[i]], 1u);
}

__global__ void __launch_bounds__(256) k_dis(const uint* __restrict__ cnt,
                                             float* __restrict__ dis, int N) {
  int i = blockIdx.x * 256 + threadIdx.x;
  if (i < N) dis[i] = rsqrtf((float)cnt[i] + 1.0f);
}

// ---------------- 3-pass scan ----------------
__global__ void __launch_bounds__(1024) k_scan1(const uint* __restrict__ cnt,
                                                uint* __restrict__ bsum, int N) {
  __shared__ uint ws[16];
  int tid = threadIdx.x;
  int i = blockIdx.x * 1024 + tid;
  uint v = (i < N) ? cnt[i] : 0u;
  #pragma unroll
  for (int d = 32; d; d >>= 1) v += __shfl_xor(v, d, 64);
  if ((tid & 63) == 0) ws[tid >> 6] = v;
  __syncthreads();
  if (tid == 0) {
    uint s = 0;
    #pragma unroll
    for (int j = 0; j < 16; ++j) s += ws[j];
    bsum[blockIdx.x] = s;
  }
}

__global__ void __launch_bounds__(128) k_scan2(const uint* __restrict__ bsum,
                                               uint* __restrict__ boff, int nb,
                                               int* __restrict__ row_ptr, int N, int E) {
  __shared__ uint w0tot;
  int tid = threadIdx.x, lane = tid & 63, wv = tid >> 6;
  uint v = (tid < nb) ? bsum[tid] : 0u;
  uint x = v;
  #pragma unroll
  for (int d = 1; d < 64; d <<= 1) {
    uint y = __shfl_up(x, (uint)d, 64);
    if (lane >= d) x += y;
  }
  if (wv == 0 && lane == 63) w0tot = x;
  __syncthreads();
  uint excl = (x - v) + (wv ? w0tot : 0u);
  if (tid < nb) boff[tid] = excl;
  if (tid == 0) row_ptr[N] = E;
}

__global__ void __launch_bounds__(1024) k_scan3(const uint* __restrict__ cnt,
                                                const uint* __restrict__ boff,
                                                int* __restrict__ row_ptr,
                                                int* __restrict__ cursor, int N) {
  __shared__ uint ws[16];
  __shared__ uint wexcl[16];
  int tid = threadIdx.x, lane = tid & 63, wv = tid >> 6;
  int i = blockIdx.x * 1024 + tid;
  uint v = (i < N) ? cnt[i] : 0u;
  uint x = v;
  #pragma unroll
  for (int d = 1; d < 64; d <<= 1) {
    uint y = __shfl_up(x, (uint)d, 64);
    if (lane >= d) x += y;
  }
  if (lane == 63) ws[wv] = x;
  __syncthreads();
  if (tid == 0) {
    uint run = 0;
    #pragma unroll
    for (int j = 0; j < 16; ++j) { uint t = ws[j]; wexcl[j] = run; run += t; }
  }
  __syncthreads();
  uint excl = boff[blockIdx.x] + wexcl[wv] + (x - v);
  if (i < N) { row_ptr[i] = (int)excl; cursor[i] = (int)excl; }
}

// ---------------- scatter: 4B records (coef-bf16 << 17 | src) ----------------
__global__ void __launch_bounds__(256) k_scatter(const int* __restrict__ src,
                                                 const int* __restrict__ dst,
                                                 const float* __restrict__ dis,
                                                 int* __restrict__ cursor,
                                                 uint* __restrict__ edges, int E) {
  int i = blockIdx.x * 256 + threadIdx.x;
  if (i < E) {
    int s = src[i], d = dst[i];
    int pos = atomicAdd(&cursor[d], 1);
    edges[pos] = (bf16_rne(dis[s] * dis[d]) << 17) | (uint)s;
  }
}

// ---------------- MFMA bf16 GEMM: Hb[M][FOUT](bf16) = X[M][128] @ W[128][FOUT] ----------------
template <int FOUT>
__global__ void __launch_bounds__(256) k_gemm(const float* __restrict__ X,
                                              const float* __restrict__ W,
                                              ushort* __restrict__ Hb, int M) {
  constexpr int NCT = FOUT / 32;
  constexpr int TPW = NCT / 2;
  __shared__ alignas(16) ushort Af[2 * 8 * 64 * 8];
  __shared__ alignas(16) ushort Wf[NCT * 8 * 64 * 8];
  int t = threadIdx.x, lane = t & 63, wv = t >> 6;
  int m0 = blockIdx.x * 64;

  {
    int m = t >> 2;
    int gm = m0 + m;
    int rb = m >> 5, ml = m & 31;
    #pragma unroll
    for (int i = 0; i < 4; ++i) {
      int g = (t & 3) + i * 4;
      float4 va = make_float4(0.f, 0.f, 0.f, 0.f), vb = va;
      if (gm < M) {
        va = *reinterpret_cast<const float4*>(X + (size_t)gm * 128 + g * 8);
        vb = *reinterpret_cast<const float4*>(X + (size_t)gm * 128 + g * 8 + 4);
      }
      uint4 p;
      p.x = bf16_rne(va.x) | (bf16_rne(va.y) << 16);
      p.y = bf16_rne(va.z) | (bf16_rne(va.w) << 16);
      p.z = bf16_rne(vb.x) | (bf16_rne(vb.y) << 16);
      p.w = bf16_rne(vb.z) | (bf16_rne(vb.w) << 16);
      int kc = g >> 1, khi = g & 1;
      int ln = khi * 32 + ml;
      *reinterpret_cast<uint4*>(&Af[(((rb * 8 + kc) * 64) + ln) * 8]) = p;
    }
  }
  {
    constexpr int ITERS = 128 * FOUT / 4 / 256;
    #pragma unroll
    for (int it = 0; it < ITERS; ++it) {
      int lin = it * 256 + t;
      int k = lin / (FOUT / 4);
      int n = (lin % (FOUT / 4)) * 4;
      float4 vw = *reinterpret_cast<const float4*>(W + (size_t)k * FOUT + n);
      int kc = k >> 4, khi = (k >> 3) & 1, j = k & 7;
      float arr[4] = {vw.x, vw.y, vw.z, vw.w};
      #pragma unroll
      for (int e = 0; e < 4; ++e) {
        int nn = n + e;
        int c = nn >> 5;
        int ln = khi * 32 + (nn & 31);
        Wf[(((c * 8 + kc) * 64) + ln) * 8 + j] = (ushort)bf16_rne(arr[e]);
      }
    }
  }
  __syncthreads();

  f32x16 acc[TPW];
  #pragma unroll
  for (int tp = 0; tp < TPW; ++tp)
    #pragma unroll
    for (int r = 0; r < 16; ++r) acc[tp][r] = 0.f;

  int rb = wv & 1, cg = wv >> 1;
  #pragma unroll
  for (int kc = 0; kc < 8; ++kc) {
    bf16x8 a = *reinterpret_cast<bf16x8*>(&Af[((rb * 8 + kc) * 64 + lane) * 8]);
    #pragma unroll
    for (int tp = 0; tp < TPW; ++tp) {
      int c = cg * TPW + tp;
      bf16x8 bb = *reinterpret_cast<bf16x8*>(&Wf[((c * 8 + kc) * 64 + lane) * 8]);
      acc[tp] = __builtin_amdgcn_mfma_f32_32x32x16_bf16(a, bb, acc[tp], 0, 0, 0);
    }
  }

  #pragma unroll
  for (int tp = 0; tp < TPW; ++tp) {
    int col = (cg * TPW + tp) * 32 + (lane & 31);
    #pragma unroll
    for (int reg = 0; reg < 16; ++reg) {
      int row = m0 + rb * 32 + 4 * (lane >> 5) + (reg & 3) + 8 * (reg >> 2);
      if (row < M) Hb[(size_t)row * FOUT + col] = (ushort)bf16_rne(acc[tp][reg]);
    }
  }
}

// ---------------- aggregate F=128: half-wave per edge, uint2 gathers ----------------
template <bool RELU>
__global__ void __launch_bounds__(256) k_agg128(const uint* __restrict__ hb,
                                                const int* __restrict__ row_ptr,
                                                const uint* __restrict__ edges,
                                                const float* __restrict__ dis,
                                                const float* __restrict__ bias,
                                                float* __restrict__ out, int N) {
  int n = blockIdx.x * 4 + (threadIdx.x >> 6);
  int lane = threadIdx.x & 63;
  if (n >= N) return;
  int beg = row_ptr[n], end = row_ptr[n + 1];
  int hw = lane >> 5, sl = lane & 31;
  const uint2* __restrict__ h2 = reinterpret_cast<const uint2*>(hb);  // 32 uint2/row

  float4 acc = make_float4(0.f, 0.f, 0.f, 0.f);
  int p = beg;
  for (; p + 16 <= end; p += 16) {
    uint r[8];
    #pragma unroll
    for (int j = 0; j < 8; ++j) r[j] = edges[p + 2 * j + hw];
    uint2 v[8];
    #pragma unroll
    for (int j = 0; j < 8; ++j) v[j] = h2[(size_t)(r[j] & 0x1ffffu) * 32 + sl];
    #pragma unroll
    for (int j = 0; j < 8; ++j) {
      float c = __uint_as_float((r[j] >> 17) << 16);
      acc.x = fmaf(blo(v[j].x), c, acc.x);
      acc.y = fmaf(bhi(v[j].x), c, acc.y);
      acc.z = fmaf(blo(v[j].y), c, acc.z);
      acc.w = fmaf(bhi(v[j].y), c, acc.w);
    }
  }
  for (; p < end; p += 2) {
    int pp = p + hw;
    if (pp < end) {
      uint r = edges[pp];
      uint2 v = h2[(size_t)(r & 0x1ffffu) * 32 + sl];
      float c = __uint_as_float((r >> 17) << 16);
      acc.x = fmaf(blo(v.x), c, acc.x);
      acc.y = fmaf(bhi(v.x), c, acc.y);
      acc.z = fmaf(blo(v.y), c, acc.z);
      acc.w = fmaf(bhi(v.y), c, acc.w);
    }
  }
  // combine halves
  acc.x += __shfl_xor(acc.x, 32, 64);
  acc.y += __shfl_xor(acc.y, 32, 64);
  acc.z += __shfl_xor(acc.z, 32, 64);
  acc.w += __shfl_xor(acc.w, 32, 64);

  float dn = dis[n];
  float sc = dn * dn;
  uint2 hv = h2[(size_t)n * 32 + sl];
  float4 b = reinterpret_cast<const float4*>(bias)[sl];
  acc.x = fmaf(sc, blo(hv.x), acc.x) + b.x;
  acc.y = fmaf(sc, bhi(hv.x), acc.y) + b.y;
  acc.z = fmaf(sc, blo(hv.y), acc.z) + b.z;
  acc.w = fmaf(sc, bhi(hv.y), acc.w) + b.w;
  if (RELU) {
    acc.x = fmaxf(acc.x, 0.f); acc.y = fmaxf(acc.y, 0.f);
    acc.z = fmaxf(acc.z, 0.f); acc.w = fmaxf(acc.w, 0.f);
  }
  if (hw == 0)
    reinterpret_cast<float4*>(out + (size_t)n * 128)[sl] = acc;
}

// ---------------- aggregate F=64 + fused log_softmax: half-wave per edge, uint gathers ----------------
__global__ void __launch_bounds__(256) k_agg64(const uint* __restrict__ hb,
                                               const int* __restrict__ row_ptr,
                                               const uint* __restrict__ edges,
                                               const float* __restrict__ dis,
                                               const float* __restrict__ bias,
                                               float* __restrict__ out, int N) {
  int n = blockIdx.x * 4 + (threadIdx.x >> 6);
  int lane = threadIdx.x & 63;
  if (n >= N) return;
  int beg = row_ptr[n], end = row_ptr[n + 1];
  int hw = lane >> 5, sl = lane & 31;
  // hb rows: 64 ushort = 32 uint
  float2 acc = make_float2(0.f, 0.f);
  int p = beg;
  for (; p + 16 <= end; p += 16) {
    uint r[8];
    #pragma unroll
    for (int j = 0; j < 8; ++j) r[j] = edges[p + 2 * j + hw];
    uint v[8];
    #pragma unroll
    for (int j = 0; j < 8; ++j) v[j] = hb[(size_t)(r[j] & 0x1ffffu) * 32 + sl];
    #pragma unroll
    for (int j = 0; j < 8; ++j) {
      float c = __uint_as_float((r[j] >> 17) << 16);
      acc.x = fmaf(blo(v[j]), c, acc.x);
      acc.y = fmaf(bhi(v[j]), c, acc.y);
    }
  }
  for (; p < end; p += 2) {
    int pp = p + hw;
    if (pp < end) {
      uint r = edges[pp];
      uint v = hb[(size_t)(r & 0x1ffffu) * 32 + sl];
      float c = __uint_as_float((r >> 17) << 16);
      acc.x = fmaf(blo(v), c, acc.x);
      acc.y = fmaf(bhi(v), c, acc.y);
    }
  }
  acc.x += __shfl_xor(acc.x, 32, 64);
  acc.y += __shfl_xor(acc.y, 32, 64);

  float dn = dis[n];
  uint hv = hb[(size_t)n * 32 + sl];
  float2 b = reinterpret_cast<const float2*>(bias)[sl];
  acc.x = fmaf(dn * dn, blo(hv), acc.x) + b.x;
  acc.y = fmaf(dn * dn, bhi(hv), acc.y) + b.y;

  // log_softmax over 64 features held as 2/lane across each 32-lane half (halves duplicate)
  float m = fmaxf(acc.x, acc.y);
  #pragma unroll
  for (int d = 16; d; d >>= 1) m = fmaxf(m, __shfl_xor(m, d, 64));
  float e = __expf(acc.x - m) + __expf(acc.y - m);
  #pragma unroll
  for (int d = 16; d; d >>= 1) e += __shfl_xor(e, d, 64);
  float lse = m + __logf(e);
  acc.x -= lse;
  acc.y -= lse;
  if (hw == 0)
    reinterpret_cast<float2*>(out + (size_t)n * 64)[sl] = acc;
}

extern "C" void kernel_launch(void* const* d_in, const int* in_sizes, int n_in,
                              void* d_out, int out_size, void* d_ws, size_t ws_size,
                              hipStream_t stream) {
  const float* x  = (const float*)d_in[0];
  const int*   ei = (const int*)d_in[1];
  const float* W0 = (const float*)d_in[2];
  const float* b0 = (const float*)d_in[3];
  const float* W1 = (const float*)d_in[4];
  const float* b1 = (const float*)d_in[5];
  const float* W2 = (const float*)d_in[6];
  const float* b2 = (const float*)d_in[7];
  float* out = (float*)d_out;

  const int N = NN, E = NE;
  const int* src = ei;
  const int* dst = ei + E;

  char* ws = (char*)d_ws;
  size_t off = 0;
  auto alloc = [&](size_t bytes) -> void* {
    off = (off + 255) & ~(size_t)255;
    void* p = ws + off;
    off += bytes;
    return p;
  };
  uint*   cnt     = (uint*)alloc((size_t)N * 4);
  float*  dis     = (float*)alloc((size_t)N * 4);
  int*    row_ptr = (int*)alloc((size_t)(N + 1) * 4);
  int*    cursor  = (int*)alloc((size_t)N * 4);
  uint*   edges   = (uint*)alloc((size_t)E * 4);
  uint*   bsum    = (uint*)alloc(128 * 4);
  uint*   boff    = (uint*)alloc(128 * 4);
  ushort* bufAb   = (ushort*)alloc((size_t)N * 128 * 2);  // bf16 GEMM out
  float*  bufB    = (float*)alloc((size_t)N * 128 * 4);   // agg out / next gemm in

  const int nb = (N + 1023) / 1024;  // 98

  // ---- CSR build ----
  hipMemsetAsync(cnt, 0, (size_t)N * 4, stream);
  k_count<<<(E + 255) / 256, 256, 0, stream>>>(dst, cnt, E);
  k_dis<<<(N + 255) / 256, 256, 0, stream>>>(cnt, dis, N);
  k_scan1<<<nb, 1024, 0, stream>>>(cnt, bsum, N);
  k_scan2<<<1, 128, 0, stream>>>(bsum, boff, nb, row_ptr, N, E);
  k_scan3<<<nb, 1024, 0, stream>>>(cnt, boff, row_ptr, cursor, N);
  k_scatter<<<(E + 255) / 256, 256, 0, stream>>>(src, dst, dis, cursor, edges, E);

  const int gemm_grid = (N + 63) / 64;   // 1563
  const int node_grid = (N + 3) / 4;     // 25000

  // ---- layer 0 ----
  k_gemm<128><<<gemm_grid, 256, 0, stream>>>(x, W0, bufAb, N);
  k_agg128<true><<<node_grid, 256, 0, stream>>>((const uint*)bufAb, row_ptr, edges, dis, b0, bufB, N);
  // ---- layer 1 ----
  k_gemm<128><<<gemm_grid, 256, 0, stream>>>(bufB, W1, bufAb, N);
  k_agg128<true><<<node_grid, 256, 0, stream>>>((const uint*)bufAb, row_ptr, edges, dis, b1, bufB, N);
  // ---- layer 2 (fused log_softmax epilogue) ----
  k_gemm<64><<<gemm_grid, 256, 0, stream>>>(bufB, W2, bufAb, N);
  k_agg64<<<node_grid, 256, 0, stream>>>((const uint*)bufAb, row_ptr, edges, dis, b2, out, N);
}

// Round 7
// 523.454 us; speedup vs baseline: 1.0608x; 1.0608x over previous
//
#include <hip/hip_runtime.h>
#include <cstddef>

#define NN 100000
#define NE 1600000
#define CB_SH 9                       // coarse bucket = 512 nodes
#define NCB ((NN + 511) >> CB_SH)     // 196 buckets
#define BIN_D 32
#define SORT_D 9216                   // mean bucket 8192 edges + ~11 sigma
#define SC_BLOCKS 384

typedef unsigned int uint;
typedef unsigned short ushort;
typedef short bf16x8 __attribute__((ext_vector_type(8)));
typedef float f32x16 __attribute__((ext_vector_type(16)));

__device__ inline uint bf16_rne(float f) {   // fp32 -> bf16 bits (round-nearest-even)
  uint u = __float_as_uint(f);
  u += 0x7fffu + ((u >> 16) & 1u);
  return u >> 16;
}
__device__ inline float blo(uint u) { return __uint_as_float(u << 16); }
__device__ inline float bhi(uint u) { return __uint_as_float(u & 0xffff0000u); }

// ---------------- degree count ----------------
__global__ void __launch_bounds__(256) k_count(const int* __restrict__ dst,
                                               uint* __restrict__ cnt, int E) {
  int i = blockIdx.x * 256 + threadIdx.x;
  if (i < E) atomicAdd(&cnt[dst[i]], 1u);
}

__global__ void __launch_bounds__(256) k_dis(const uint* __restrict__ cnt,
                                             float* __restrict__ dis, int N) {
  int i = blockIdx.x * 256 + threadIdx.x;
  if (i < N) dis[i] = rsqrtf((float)cnt[i] + 1.0f);
}

// ---------------- 3-pass scan -> row_ptr ----------------
__global__ void __launch_bounds__(1024) k_scan1(const uint* __restrict__ cnt,
                                                uint* __restrict__ bsum, int N) {
  __shared__ uint ws[16];
  int tid = threadIdx.x;
  int i = blockIdx.x * 1024 + tid;
  uint v = (i < N) ? cnt[i] : 0u;
  #pragma unroll
  for (int d = 32; d; d >>= 1) v += __shfl_xor(v, d, 64);
  if ((tid & 63) == 0) ws[tid >> 6] = v;
  __syncthreads();
  if (tid == 0) {
    uint s = 0;
    #pragma unroll
    for (int j = 0; j < 16; ++j) s += ws[j];
    bsum[blockIdx.x] = s;
  }
}

__global__ void __launch_bounds__(128) k_scan2(const uint* __restrict__ bsum,
                                               uint* __restrict__ boff, int nb,
                                               int* __restrict__ row_ptr, int N, int E) {
  __shared__ uint w0tot;
  int tid = threadIdx.x, lane = tid & 63, wv = tid >> 6;
  uint v = (tid < nb) ? bsum[tid] : 0u;
  uint x = v;
  #pragma unroll
  for (int d = 1; d < 64; d <<= 1) {
    uint y = __shfl_up(x, (uint)d, 64);
    if (lane >= d) x += y;
  }
  if (wv == 0 && lane == 63) w0tot = x;
  __syncthreads();
  uint excl = (x - v) + (wv ? w0tot : 0u);
  if (tid < nb) boff[tid] = excl;
  if (tid == 0) row_ptr[N] = E;
}

__global__ void __launch_bounds__(1024) k_scan3(const uint* __restrict__ cnt,
                                                const uint* __restrict__ boff,
                                                int* __restrict__ row_ptr, int N) {
  __shared__ uint ws[16];
  __shared__ uint wexcl[16];
  int tid = threadIdx.x, lane = tid & 63, wv = tid >> 6;
  int i = blockIdx.x * 1024 + tid;
  uint v = (i < N) ? cnt[i] : 0u;
  uint x = v;
  #pragma unroll
  for (int d = 1; d < 64; d <<= 1) {
    uint y = __shfl_up(x, (uint)d, 64);
    if (lane >= d) x += y;
  }
  if (lane == 63) ws[wv] = x;
  __syncthreads();
  if (tid == 0) {
    uint run = 0;
    #pragma unroll
    for (int j = 0; j < 16; ++j) { uint t = ws[j]; wexcl[j] = run; run += t; }
  }
  __syncthreads();
  uint excl = boff[blockIdx.x] + wexcl[wv] + (x - v);
  if (i < N) row_ptr[i] = (int)excl;
}

__global__ void __launch_bounds__(256) k_gcur(const int* __restrict__ row_ptr,
                                              int* __restrict__ gcur) {
  int t = threadIdx.x;
  if (t < NCB) gcur[t] = row_ptr[min(t << CB_SH, NN)];
}

// ---------------- pass A: bin edges into 196 coarse buckets, clustered writes ----------------
// record: src (17b) | dst-low-9 (bits 17..25)
__global__ void __launch_bounds__(256) k_binA(const int* __restrict__ src,
                                              const int* __restrict__ dst,
                                              int* __restrict__ gcur,
                                              uint* __restrict__ ebuf, int E) {
  __shared__ uint bins[NCB][BIN_D + 1];   // +1 pad: spread banks
  __shared__ uint bcnt[NCB];
  int t = threadIdx.x;
  for (int j = t; j < NCB; j += 256) bcnt[j] = 0;
  const int per = (E + SC_BLOCKS - 1) / SC_BLOCKS;
  int e0 = blockIdx.x * per, e1 = min(E, e0 + per);
  __syncthreads();
  for (int rb = e0; rb < e1; rb += 2048) {
    #pragma unroll
    for (int r = 0; r < 8; ++r) {
      int i = rb + r * 256 + t;
      if (i < e1) {
        uint s = (uint)src[i], d = (uint)dst[i];
        uint b = d >> CB_SH;
        uint rec = s | ((d & 511u) << 17);
        uint slot = atomicAdd(&bcnt[b], 1u);
        if (slot < BIN_D) bins[b][slot] = rec;
        else ebuf[atomicAdd(&gcur[b], 1)] = rec;     // rare overflow: exact slot
      }
    }
    __syncthreads();
    if (t < NCB) {                      // one thread per bucket: parallel flush
      uint c = bcnt[t]; if (c > BIN_D) c = BIN_D;
      if (c) {
        int base = atomicAdd(&gcur[t], (int)c);
        for (uint i = 0; i < c; ++i) ebuf[base + i] = bins[t][i];
      }
      bcnt[t] = 0;
    }
    __syncthreads();
  }
}

// ---------------- pass B: per-bucket counting sort via row_ptr prefix -> final CSR ----------------
__global__ void __launch_bounds__(256) k_sortB(const uint* __restrict__ ebuf,
                                               const int* __restrict__ row_ptr,
                                               const float* __restrict__ dis,
                                               uint* __restrict__ edges, int N) {
  __shared__ uint sbuf[SORT_D];         // 36 KB
  __shared__ int lcur[512];
  __shared__ float disl[512];
  int b = blockIdx.x, t = threadIdx.x;
  int node0 = b << CB_SH;
  int ebase = row_ptr[node0];
  int eend  = row_ptr[min(node0 + 512, N)];
  for (int j = t; j < 512; j += 256) {
    int g = node0 + j;
    lcur[j] = (g < N) ? (row_ptr[g] - ebase) : 0;
    disl[j] = (g < N) ? dis[g] : 0.f;
  }
  __syncthreads();
  int cnt = eend - ebase;
  for (int i = t; i < cnt; i += 256) {
    uint rec = ebuf[ebase + i];
    uint s = rec & 0x1ffffu;
    uint dl = rec >> 17;
    float coef = dis[s] * disl[dl];
    uint orec = (bf16_rne(coef) << 17) | s;
    int pos = atomicAdd(&lcur[dl], 1);
    if (pos < SORT_D) sbuf[pos] = orec;
    else edges[ebase + pos] = orec;     // overflow: exact slot
  }
  __syncthreads();
  int lim = min(cnt, SORT_D);
  for (int i = t; i < lim; i += 256)
    edges[ebase + i] = sbuf[i];
}

// ---------------- MFMA bf16 GEMM: Hb[M][FOUT](bf16) = X[M][128] @ W[128][FOUT] ----------------
template <int FOUT, bool BF16IN>
__global__ void __launch_bounds__(256) k_gemm(const void* __restrict__ Xv,
                                              const float* __restrict__ W,
                                              ushort* __restrict__ Hb, int M) {
  constexpr int NCT = FOUT / 32;
  constexpr int TPW = NCT / 2;
  __shared__ alignas(16) ushort Af[2 * 8 * 64 * 8];
  __shared__ alignas(16) ushort Wf[NCT * 8 * 64 * 8];
  int t = threadIdx.x, lane = t & 63, wv = t >> 6;
  int m0 = blockIdx.x * 64;

  {
    int m = t >> 2;
    int gm = m0 + m;
    int rb = m >> 5, ml = m & 31;
    #pragma unroll
    for (int i = 0; i < 4; ++i) {
      int g = (t & 3) + i * 4;            // g = k>>3 in 0..15
      uint4 p = make_uint4(0u, 0u, 0u, 0u);
      if (gm < M) {
        if (BF16IN) {
          const ushort* X = (const ushort*)Xv;
          p = *reinterpret_cast<const uint4*>(X + (size_t)gm * 128 + g * 8);
        } else {
          const float* X = (const float*)Xv;
          float4 va = *reinterpret_cast<const float4*>(X + (size_t)gm * 128 + g * 8);
          float4 vb = *reinterpret_cast<const float4*>(X + (size_t)gm * 128 + g * 8 + 4);
          p.x = bf16_rne(va.x) | (bf16_rne(va.y) << 16);
          p.y = bf16_rne(va.z) | (bf16_rne(va.w) << 16);
          p.z = bf16_rne(vb.x) | (bf16_rne(vb.y) << 16);
          p.w = bf16_rne(vb.z) | (bf16_rne(vb.w) << 16);
        }
      }
      int kc = g >> 1, khi = g & 1;
      int ln = khi * 32 + ml;
      *reinterpret_cast<uint4*>(&Af[(((rb * 8 + kc) * 64) + ln) * 8]) = p;
    }
  }
  {
    constexpr int ITERS = 128 * FOUT / 4 / 256;
    #pragma unroll
    for (int it = 0; it < ITERS; ++it) {
      int lin = it * 256 + t;
      int k = lin / (FOUT / 4);
      int n = (lin % (FOUT / 4)) * 4;
      float4 vw = *reinterpret_cast<const float4*>(W + (size_t)k * FOUT + n);
      int kc = k >> 4, khi = (k >> 3) & 1, j = k & 7;
      float arr[4] = {vw.x, vw.y, vw.z, vw.w};
      #pragma unroll
      for (int e = 0; e < 4; ++e) {
        int nn = n + e;
        int c = nn >> 5;
        int ln = khi * 32 + (nn & 31);
        Wf[(((c * 8 + kc) * 64) + ln) * 8 + j] = (ushort)bf16_rne(arr[e]);
      }
    }
  }
  __syncthreads();

  f32x16 acc[TPW];
  #pragma unroll
  for (int tp = 0; tp < TPW; ++tp)
    #pragma unroll
    for (int r = 0; r < 16; ++r) acc[tp][r] = 0.f;

  int rb = wv & 1, cg = wv >> 1;
  #pragma unroll
  for (int kc = 0; kc < 8; ++kc) {
    bf16x8 a = *reinterpret_cast<bf16x8*>(&Af[((rb * 8 + kc) * 64 + lane) * 8]);
    #pragma unroll
    for (int tp = 0; tp < TPW; ++tp) {
      int c = cg * TPW + tp;
      bf16x8 bb = *reinterpret_cast<bf16x8*>(&Wf[((c * 8 + kc) * 64 + lane) * 8]);
      acc[tp] = __builtin_amdgcn_mfma_f32_32x32x16_bf16(a, bb, acc[tp], 0, 0, 0);
    }
  }

  // C/D layout: col=lane&31, row=(reg&3)+8*(reg>>2)+4*(lane>>5)
  #pragma unroll
  for (int tp = 0; tp < TPW; ++tp) {
    int col = (cg * TPW + tp) * 32 + (lane & 31);
    #pragma unroll
    for (int reg = 0; reg < 16; ++reg) {
      int row = m0 + rb * 32 + 4 * (lane >> 5) + (reg & 3) + 8 * (reg >> 2);
      if (row < M) Hb[(size_t)row * FOUT + col] = (ushort)bf16_rne(acc[tp][reg]);
    }
  }
}

// ---------------- aggregate F=128: half-wave per edge, bf16 in, bf16 out ----------------
__global__ void __launch_bounds__(256) k_agg128(const uint* __restrict__ hb,
                                                const int* __restrict__ row_ptr,
                                                const uint* __restrict__ edges,
                                                const float* __restrict__ dis,
                                                const float* __restrict__ bias,
                                                uint* __restrict__ outb, int N) {
  int n = blockIdx.x * 4 + (threadIdx.x >> 6);
  int lane = threadIdx.x & 63;
  if (n >= N) return;
  int beg = row_ptr[n], end = row_ptr[n + 1];
  int hw = lane >> 5, sl = lane & 31;
  const uint2* __restrict__ h2 = reinterpret_cast<const uint2*>(hb);  // 32 uint2/row

  float4 acc = make_float4(0.f, 0.f, 0.f, 0.f);
  int p = beg;
  for (; p + 16 <= end; p += 16) {
    uint r[8];
    #pragma unroll
    for (int j = 0; j < 8; ++j) r[j] = edges[p + 2 * j + hw];
    uint2 v[8];
    #pragma unroll
    for (int j = 0; j < 8; ++j) v[j] = h2[(size_t)(r[j] & 0x1ffffu) * 32 + sl];
    #pragma unroll
    for (int j = 0; j < 8; ++j) {
      float c = __uint_as_float((r[j] >> 17) << 16);
      acc.x = fmaf(blo(v[j].x), c, acc.x);
      acc.y = fmaf(bhi(v[j].x), c, acc.y);
      acc.z = fmaf(blo(v[j].y), c, acc.z);
      acc.w = fmaf(bhi(v[j].y), c, acc.w);
    }
  }
  for (; p < end; p += 2) {
    int pp = p + hw;
    if (pp < end) {
      uint r = edges[pp];
      uint2 v = h2[(size_t)(r & 0x1ffffu) * 32 + sl];
      float c = __uint_as_float((r >> 17) << 16);
      acc.x = fmaf(blo(v.x), c, acc.x);
      acc.y = fmaf(bhi(v.x), c, acc.y);
      acc.z = fmaf(blo(v.y), c, acc.z);
      acc.w = fmaf(bhi(v.y), c, acc.w);
    }
  }
  acc.x += __shfl_xor(acc.x, 32, 64);
  acc.y += __shfl_xor(acc.y, 32, 64);
  acc.z += __shfl_xor(acc.z, 32, 64);
  acc.w += __shfl_xor(acc.w, 32, 64);

  float dn = dis[n];
  float sc = dn * dn;
  uint2 hv = h2[(size_t)n * 32 + sl];
  float4 b = reinterpret_cast<const float4*>(bias)[sl];
  acc.x = fmaxf(fmaf(sc, blo(hv.x), acc.x) + b.x, 0.f);   // ReLU fused
  acc.y = fmaxf(fmaf(sc, bhi(hv.x), acc.y) + b.y, 0.f);
  acc.z = fmaxf(fmaf(sc, blo(hv.y), acc.z) + b.z, 0.f);
  acc.w = fmaxf(fmaf(sc, bhi(hv.y), acc.w) + b.w, 0.f);
  if (hw == 0) {
    uint2 pb;
    pb.x = bf16_rne(acc.x) | (bf16_rne(acc.y) << 16);
    pb.y = bf16_rne(acc.z) | (bf16_rne(acc.w) << 16);
    reinterpret_cast<uint2*>(outb + (size_t)n * 64)[sl] = pb;
  }
}

// ---------------- aggregate F=64 + fused log_softmax ----------------
__global__ void __launch_bounds__(256) k_agg64(const uint* __restrict__ hb,
                                               const int* __restrict__ row_ptr,
                                               const uint* __restrict__ edges,
                                               const float* __restrict__ dis,
                                               const float* __restrict__ bias,
                                               float* __restrict__ out, int N) {
  int n = blockIdx.x * 4 + (threadIdx.x >> 6);
  int lane = threadIdx.x & 63;
  if (n >= N) return;
  int beg = row_ptr[n], end = row_ptr[n + 1];
  int hw = lane >> 5, sl = lane & 31;
  float2 acc = make_float2(0.f, 0.f);
  int p = beg;
  for (; p + 16 <= end; p += 16) {
    uint r[8];
    #pragma unroll
    for (int j = 0; j < 8; ++j) r[j] = edges[p + 2 * j + hw];
    uint v[8];
    #pragma unroll
    for (int j = 0; j < 8; ++j) v[j] = hb[(size_t)(r[j] & 0x1ffffu) * 32 + sl];
    #pragma unroll
    for (int j = 0; j < 8; ++j) {
      float c = __uint_as_float((r[j] >> 17) << 16);
      acc.x = fmaf(blo(v[j]), c, acc.x);
      acc.y = fmaf(bhi(v[j]), c, acc.y);
    }
  }
  for (; p < end; p += 2) {
    int pp = p + hw;
    if (pp < end) {
      uint r = edges[pp];
      uint v = hb[(size_t)(r & 0x1ffffu) * 32 + sl];
      float c = __uint_as_float((r >> 17) << 16);
      acc.x = fmaf(blo(v), c, acc.x);
      acc.y = fmaf(bhi(v), c, acc.y);
    }
  }
  acc.x += __shfl_xor(acc.x, 32, 64);
  acc.y += __shfl_xor(acc.y, 32, 64);

  float dn = dis[n];
  uint hv = hb[(size_t)n * 32 + sl];
  float2 b = reinterpret_cast<const float2*>(bias)[sl];
  acc.x = fmaf(dn * dn, blo(hv), acc.x) + b.x;
  acc.y = fmaf(dn * dn, bhi(hv), acc.y) + b.y;

  float m = fmaxf(acc.x, acc.y);
  #pragma unroll
  for (int d = 16; d; d >>= 1) m = fmaxf(m, __shfl_xor(m, d, 64));
  float e = __expf(acc.x - m) + __expf(acc.y - m);
  #pragma unroll
  for (int d = 16; d; d >>= 1) e += __shfl_xor(e, d, 64);
  float lse = m + __logf(e);
  acc.x -= lse;
  acc.y -= lse;
  if (hw == 0)
    reinterpret_cast<float2*>(out + (size_t)n * 64)[sl] = acc;
}

extern "C" void kernel_launch(void* const* d_in, const int* in_sizes, int n_in,
                              void* d_out, int out_size, void* d_ws, size_t ws_size,
                              hipStream_t stream) {
  const float* x  = (const float*)d_in[0];
  const int*   ei = (const int*)d_in[1];
  const float* W0 = (const float*)d_in[2];
  const float* b0 = (const float*)d_in[3];
  const float* W1 = (const float*)d_in[4];
  const float* b1 = (const float*)d_in[5];
  const float* W2 = (const float*)d_in[6];
  const float* b2 = (const float*)d_in[7];
  float* out = (float*)d_out;

  const int N = NN, E = NE;
  const int* src = ei;
  const int* dst = ei + E;

  char* ws = (char*)d_ws;
  size_t off = 0;
  auto alloc = [&](size_t bytes) -> void* {
    off = (off + 255) & ~(size_t)255;
    void* p = ws + off;
    off += bytes;
    return p;
  };
  uint*   cnt     = (uint*)alloc((size_t)N * 4);
  float*  dis     = (float*)alloc((size_t)N * 4);
  int*    row_ptr = (int*)alloc((size_t)(N + 1) * 4);
  int*    gcur    = (int*)alloc((size_t)NCB * 4);
  uint*   ebuf    = (uint*)alloc((size_t)E * 4);
  uint*   edges   = (uint*)alloc((size_t)E * 4);
  uint*   bsum    = (uint*)alloc(128 * 4);
  uint*   boff    = (uint*)alloc(128 * 4);
  ushort* bufAb   = (ushort*)alloc((size_t)N * 128 * 2);  // gemm bf16 out
  ushort* bufBb   = (ushort*)alloc((size_t)N * 128 * 2);  // agg bf16 out / gemm in

  const int nb = (N + 1023) / 1024;  // 98

  // ---- CSR build ----
  hipMemsetAsync(cnt, 0, (size_t)N * 4, stream);
  k_count<<<(E + 255) / 256, 256, 0, stream>>>(dst, cnt, E);
  k_dis<<<(N + 255) / 256, 256, 0, stream>>>(cnt, dis, N);
  k_scan1<<<nb, 1024, 0, stream>>>(cnt, bsum, N);
  k_scan2<<<1, 128, 0, stream>>>(bsum, boff, nb, row_ptr, N, E);
  k_scan3<<<nb, 1024, 0, stream>>>(cnt, boff, row_ptr, N);
  k_gcur<<<1, 256, 0, stream>>>(row_ptr, gcur);
  k_binA<<<SC_BLOCKS, 256, 0, stream>>>(src, dst, gcur, ebuf, E);
  k_sortB<<<NCB, 256, 0, stream>>>(ebuf, row_ptr, dis, edges, N);

  const int gemm_grid = (N + 63) / 64;   // 1563
  const int node_grid = (N + 3) / 4;     // 25000

  // ---- layer 0 ----
  k_gemm<128, false><<<gemm_grid, 256, 0, stream>>>(x, W0, bufAb, N);
  k_agg128<<<node_grid, 256, 0, stream>>>((const uint*)bufAb, row_ptr, edges, dis, b0, (uint*)bufBb, N);
  // ---- layer 1 ----
  k_gemm<128, true><<<gemm_grid, 256, 0, stream>>>(bufBb, W1, bufAb, N);
  k_agg128<<<node_grid, 256, 0, stream>>>((const uint*)bufAb, row_ptr, edges, dis, b1, (uint*)bufBb, N);
  // ---- layer 2 (fused log_softmax epilogue) ----
  k_gemm<64, true><<<gemm_grid, 256, 0, stream>>>(bufBb, W2, bufAb, N);
  k_agg64<<<node_grid, 256, 0, stream>>>((const uint*)bufAb, row_ptr, edges, dis, b2, out, N);
}

// Round 8
// 511.500 us; speedup vs baseline: 1.0856x; 1.0234x over previous
//
#include <hip/hip_runtime.h>
#include <cstddef>

#define NN 100000
#define NE 1600000
#define CB_SH 9                       // coarse bucket = 512 nodes
#define NCB ((NN + 511) >> CB_SH)     // 196 buckets
#define BIN_D 32
#define CAP 8960                      // per-bucket ebuf capacity (mean 8192 + 8.5 sigma)
#define SORT_D CAP
#define SC_BLOCKS 768

typedef unsigned int uint;
typedef unsigned short ushort;
typedef short bf16x8 __attribute__((ext_vector_type(8)));
typedef float f32x16 __attribute__((ext_vector_type(16)));

__device__ inline uint bf16_rne(float f) {   // fp32 -> bf16 bits (round-nearest-even)
  uint u = __float_as_uint(f);
  u += 0x7fffu + ((u >> 16) & 1u);
  return u >> 16;
}
__device__ inline float blo(uint u) { return __uint_as_float(u << 16); }
__device__ inline float bhi(uint u) { return __uint_as_float(u & 0xffff0000u); }

// ---------------- init: cnt=0, bucket cursors ----------------
__global__ void __launch_bounds__(256) k_init(uint* __restrict__ cnt,
                                              int* __restrict__ gcur) {
  int i = blockIdx.x * 256 + threadIdx.x;
  if (i < NN) cnt[i] = 0;
  if (i < NCB) gcur[i] = i * CAP;
}

// ---------------- pass A: bin into coarse buckets + degree count (fused) ----------------
// record: src (17b) | dst-low-9 (bits 17..25)
__global__ void __launch_bounds__(256) k_binA(const int* __restrict__ src,
                                              const int* __restrict__ dst,
                                              uint* __restrict__ cnt,
                                              int* __restrict__ gcur,
                                              uint* __restrict__ ebuf, int E) {
  __shared__ uint bins[NCB][BIN_D + 1];   // +1 pad
  __shared__ uint bcnt[NCB];
  int t = threadIdx.x;
  for (int j = t; j < NCB; j += 256) bcnt[j] = 0;
  const int per = (E + SC_BLOCKS - 1) / SC_BLOCKS;
  int e0 = blockIdx.x * per, e1 = min(E, e0 + per);
  __syncthreads();
  for (int rb = e0; rb < e1; rb += 2048) {
    #pragma unroll
    for (int r = 0; r < 8; ++r) {
      int i = rb + r * 256 + t;
      if (i < e1) {
        uint s = (uint)src[i], d = (uint)dst[i];
        atomicAdd(&cnt[d], 1u);
        uint b = d >> CB_SH;
        uint rec = s | ((d & 511u) << 17);
        uint slot = atomicAdd(&bcnt[b], 1u);
        if (slot < BIN_D) bins[b][slot] = rec;
        else ebuf[atomicAdd(&gcur[b], 1)] = rec;     // rare overflow: exact slot
      }
    }
    __syncthreads();
    if (t < NCB) {                      // one thread per bucket: parallel flush
      uint c = bcnt[t]; if (c > BIN_D) c = BIN_D;
      if (c) {
        int base = atomicAdd(&gcur[t], (int)c);
        for (uint i = 0; i < c; ++i) ebuf[base + i] = bins[t][i];
      }
      bcnt[t] = 0;
    }
    __syncthreads();
  }
}

// ---------------- 3-pass scan -> row_ptr (+dis fused in pass 1) ----------------
__global__ void __launch_bounds__(1024) k_scan1(const uint* __restrict__ cnt,
                                                uint* __restrict__ bsum,
                                                float* __restrict__ dis, int N) {
  __shared__ uint ws[16];
  int tid = threadIdx.x;
  int i = blockIdx.x * 1024 + tid;
  uint v = (i < N) ? cnt[i] : 0u;
  if (i < N) dis[i] = rsqrtf((float)v + 1.0f);
  #pragma unroll
  for (int d = 32; d; d >>= 1) v += __shfl_xor(v, d, 64);
  if ((tid & 63) == 0) ws[tid >> 6] = v;
  __syncthreads();
  if (tid == 0) {
    uint s = 0;
    #pragma unroll
    for (int j = 0; j < 16; ++j) s += ws[j];
    bsum[blockIdx.x] = s;
  }
}

__global__ void __launch_bounds__(128) k_scan2(const uint* __restrict__ bsum,
                                               uint* __restrict__ boff, int nb,
                                               int* __restrict__ row_ptr, int N, int E) {
  __shared__ uint w0tot;
  int tid = threadIdx.x, lane = tid & 63, wv = tid >> 6;
  uint v = (tid < nb) ? bsum[tid] : 0u;
  uint x = v;
  #pragma unroll
  for (int d = 1; d < 64; d <<= 1) {
    uint y = __shfl_up(x, (uint)d, 64);
    if (lane >= d) x += y;
  }
  if (wv == 0 && lane == 63) w0tot = x;
  __syncthreads();
  uint excl = (x - v) + (wv ? w0tot : 0u);
  if (tid < nb) boff[tid] = excl;
  if (tid == 0) row_ptr[N] = E;
}

__global__ void __launch_bounds__(1024) k_scan3(const uint* __restrict__ cnt,
                                                const uint* __restrict__ boff,
                                                int* __restrict__ row_ptr, int N) {
  __shared__ uint ws[16];
  __shared__ uint wexcl[16];
  int tid = threadIdx.x, lane = tid & 63, wv = tid >> 6;
  int i = blockIdx.x * 1024 + tid;
  uint v = (i < N) ? cnt[i] : 0u;
  uint x = v;
  #pragma unroll
  for (int d = 1; d < 64; d <<= 1) {
    uint y = __shfl_up(x, (uint)d, 64);
    if (lane >= d) x += y;
  }
  if (lane == 63) ws[wv] = x;
  __syncthreads();
  if (tid == 0) {
    uint run = 0;
    #pragma unroll
    for (int j = 0; j < 16; ++j) { uint t = ws[j]; wexcl[j] = run; run += t; }
  }
  __syncthreads();
  uint excl = boff[blockIdx.x] + wexcl[wv] + (x - v);
  if (i < N) row_ptr[i] = (int)excl;
}

// ---------------- pass B: per-bucket counting sort via row_ptr prefix -> final CSR ----------------
__global__ void __launch_bounds__(512) k_sortB(const uint* __restrict__ ebuf,
                                               const int* __restrict__ gcur,
                                               const int* __restrict__ row_ptr,
                                               const float* __restrict__ dis,
                                               uint* __restrict__ edges, int N) {
  __shared__ uint sbuf[SORT_D];         // 35 KB
  __shared__ int lcur[512];
  __shared__ float disl[512];
  int b = blockIdx.x, t = threadIdx.x;
  int node0 = b << CB_SH;
  int ebase = row_ptr[node0];
  int g = node0 + t;
  lcur[t] = (g < N) ? (row_ptr[g] - ebase) : 0;
  disl[t] = (g < N) ? dis[g] : 0.f;
  __syncthreads();
  int cntb = gcur[b] - b * CAP;
  const uint* __restrict__ eb = ebuf + (size_t)b * CAP;
  int i = t;
  for (; i + 3 * 512 < cntb; i += 4 * 512) {   // 4-deep pipeline on random dis reads
    uint rec[4]; float ds[4];
    #pragma unroll
    for (int j = 0; j < 4; ++j) rec[j] = eb[i + j * 512];
    #pragma unroll
    for (int j = 0; j < 4; ++j) ds[j] = dis[rec[j] & 0x1ffffu];
    #pragma unroll
    for (int j = 0; j < 4; ++j) {
      uint dl = rec[j] >> 17;
      uint orec = (bf16_rne(ds[j] * disl[dl]) << 17) | (rec[j] & 0x1ffffu);
      int pos = atomicAdd(&lcur[dl], 1);
      if (pos < SORT_D) sbuf[pos] = orec;
      else edges[ebase + pos] = orec;
    }
  }
  for (; i < cntb; i += 512) {
    uint rec = eb[i];
    uint dl = rec >> 17;
    uint orec = (bf16_rne(dis[rec & 0x1ffffu] * disl[dl]) << 17) | (rec & 0x1ffffu);
    int pos = atomicAdd(&lcur[dl], 1);
    if (pos < SORT_D) sbuf[pos] = orec;
    else edges[ebase + pos] = orec;
  }
  __syncthreads();
  int lim = min(cntb, SORT_D);
  for (int j = t; j < lim; j += 512)
    edges[ebase + j] = sbuf[j];
}

// ---------------- MFMA bf16 GEMM: Hb[M][FOUT](bf16) = X[M][128] @ W[128][FOUT] ----------------
template <int FOUT, bool BF16IN>
__global__ void __launch_bounds__(256) k_gemm(const void* __restrict__ Xv,
                                              const float* __restrict__ W,
                                              ushort* __restrict__ Hb, int M) {
  constexpr int NCT = FOUT / 32;
  constexpr int TPW = NCT / 2;
  __shared__ alignas(16) ushort Af[2 * 8 * 64 * 8];
  __shared__ alignas(16) ushort Wf[NCT * 8 * 64 * 8];
  int t = threadIdx.x, lane = t & 63, wv = t >> 6;
  int m0 = blockIdx.x * 64;

  {
    int m = t >> 2;
    int gm = m0 + m;
    int rb = m >> 5, ml = m & 31;
    #pragma unroll
    for (int i = 0; i < 4; ++i) {
      int g = (t & 3) + i * 4;            // g = k>>3 in 0..15
      uint4 p = make_uint4(0u, 0u, 0u, 0u);
      if (gm < M) {
        if (BF16IN) {
          const ushort* X = (const ushort*)Xv;
          p = *reinterpret_cast<const uint4*>(X + (size_t)gm * 128 + g * 8);
        } else {
          const float* X = (const float*)Xv;
          float4 va = *reinterpret_cast<const float4*>(X + (size_t)gm * 128 + g * 8);
          float4 vb = *reinterpret_cast<const float4*>(X + (size_t)gm * 128 + g * 8 + 4);
          p.x = bf16_rne(va.x) | (bf16_rne(va.y) << 16);
          p.y = bf16_rne(va.z) | (bf16_rne(va.w) << 16);
          p.z = bf16_rne(vb.x) | (bf16_rne(vb.y) << 16);
          p.w = bf16_rne(vb.z) | (bf16_rne(vb.w) << 16);
        }
      }
      int kc = g >> 1, khi = g & 1;
      int ln = khi * 32 + ml;
      *reinterpret_cast<uint4*>(&Af[(((rb * 8 + kc) * 64) + ln) * 8]) = p;
    }
  }
  {
    constexpr int ITERS = 128 * FOUT / 4 / 256;
    #pragma unroll
    for (int it = 0; it < ITERS; ++it) {
      int lin = it * 256 + t;
      int k = lin / (FOUT / 4);
      int n = (lin % (FOUT / 4)) * 4;
      float4 vw = *reinterpret_cast<const float4*>(W + (size_t)k * FOUT + n);
      int kc = k >> 4, khi = (k >> 3) & 1, j = k & 7;
      float arr[4] = {vw.x, vw.y, vw.z, vw.w};
      #pragma unroll
      for (int e = 0; e < 4; ++e) {
        int nn = n + e;
        int c = nn >> 5;
        int ln = khi * 32 + (nn & 31);
        Wf[(((c * 8 + kc) * 64) + ln) * 8 + j] = (ushort)bf16_rne(arr[e]);
      }
    }
  }
  __syncthreads();

  f32x16 acc[TPW];
  #pragma unroll
  for (int tp = 0; tp < TPW; ++tp)
    #pragma unroll
    for (int r = 0; r < 16; ++r) acc[tp][r] = 0.f;

  int rb = wv & 1, cg = wv >> 1;
  #pragma unroll
  for (int kc = 0; kc < 8; ++kc) {
    bf16x8 a = *reinterpret_cast<bf16x8*>(&Af[((rb * 8 + kc) * 64 + lane) * 8]);
    #pragma unroll
    for (int tp = 0; tp < TPW; ++tp) {
      int c = cg * TPW + tp;
      bf16x8 bb = *reinterpret_cast<bf16x8*>(&Wf[((c * 8 + kc) * 64 + lane) * 8]);
      acc[tp] = __builtin_amdgcn_mfma_f32_32x32x16_bf16(a, bb, acc[tp], 0, 0, 0);
    }
  }

  // C/D layout: col=lane&31, row=(reg&3)+8*(reg>>2)+4*(lane>>5)
  #pragma unroll
  for (int tp = 0; tp < TPW; ++tp) {
    int col = (cg * TPW + tp) * 32 + (lane & 31);
    #pragma unroll
    for (int reg = 0; reg < 16; ++reg) {
      int row = m0 + rb * 32 + 4 * (lane >> 5) + (reg & 3) + 8 * (reg >> 2);
      if (row < M) Hb[(size_t)row * FOUT + col] = (ushort)bf16_rne(acc[tp][reg]);
    }
  }
}

// ---------------- aggregate F=128: half-wave per edge, bf16 in, bf16 out ----------------
__global__ void __launch_bounds__(256) k_agg128(const uint* __restrict__ hb,
                                                const int* __restrict__ row_ptr,
                                                const uint* __restrict__ edges,
                                                const float* __restrict__ dis,
                                                const float* __restrict__ bias,
                                                uint* __restrict__ outb, int N) {
  int n = blockIdx.x * 4 + (threadIdx.x >> 6);
  int lane = threadIdx.x & 63;
  if (n >= N) return;
  int beg = row_ptr[n], end = row_ptr[n + 1];
  int hw = lane >> 5, sl = lane & 31;
  const uint2* __restrict__ h2 = reinterpret_cast<const uint2*>(hb);  // 32 uint2/row

  float4 acc = make_float4(0.f, 0.f, 0.f, 0.f);
  int p = beg;
  for (; p + 16 <= end; p += 16) {
    uint r[8];
    #pragma unroll
    for (int j = 0; j < 8; ++j) r[j] = edges[p + 2 * j + hw];
    uint2 v[8];
    #pragma unroll
    for (int j = 0; j < 8; ++j) v[j] = h2[(size_t)(r[j] & 0x1ffffu) * 32 + sl];
    #pragma unroll
    for (int j = 0; j < 8; ++j) {
      float c = __uint_as_float((r[j] >> 17) << 16);
      acc.x = fmaf(blo(v[j].x), c, acc.x);
      acc.y = fmaf(bhi(v[j].x), c, acc.y);
      acc.z = fmaf(blo(v[j].y), c, acc.z);
      acc.w = fmaf(bhi(v[j].y), c, acc.w);
    }
  }
  for (; p < end; p += 2) {
    int pp = p + hw;
    if (pp < end) {
      uint r = edges[pp];
      uint2 v = h2[(size_t)(r & 0x1ffffu) * 32 + sl];
      float c = __uint_as_float((r >> 17) << 16);
      acc.x = fmaf(blo(v.x), c, acc.x);
      acc.y = fmaf(bhi(v.x), c, acc.y);
      acc.z = fmaf(blo(v.y), c, acc.z);
      acc.w = fmaf(bhi(v.y), c, acc.w);
    }
  }
  acc.x += __shfl_xor(acc.x, 32, 64);
  acc.y += __shfl_xor(acc.y, 32, 64);
  acc.z += __shfl_xor(acc.z, 32, 64);
  acc.w += __shfl_xor(acc.w, 32, 64);

  float dn = dis[n];
  float sc = dn * dn;
  uint2 hv = h2[(size_t)n * 32 + sl];
  float4 b = reinterpret_cast<const float4*>(bias)[sl];
  acc.x = fmaxf(fmaf(sc, blo(hv.x), acc.x) + b.x, 0.f);   // ReLU fused
  acc.y = fmaxf(fmaf(sc, bhi(hv.x), acc.y) + b.y, 0.f);
  acc.z = fmaxf(fmaf(sc, blo(hv.y), acc.z) + b.z, 0.f);
  acc.w = fmaxf(fmaf(sc, bhi(hv.y), acc.w) + b.w, 0.f);
  if (hw == 0) {
    uint2 pb;
    pb.x = bf16_rne(acc.x) | (bf16_rne(acc.y) << 16);
    pb.y = bf16_rne(acc.z) | (bf16_rne(acc.w) << 16);
    reinterpret_cast<uint2*>(outb + (size_t)n * 64)[sl] = pb;
  }
}

// ---------------- aggregate F=64 + fused log_softmax ----------------
__global__ void __launch_bounds__(256) k_agg64(const uint* __restrict__ hb,
                                               const int* __restrict__ row_ptr,
                                               const uint* __restrict__ edges,
                                               const float* __restrict__ dis,
                                               const float* __restrict__ bias,
                                               float* __restrict__ out, int N) {
  int n = blockIdx.x * 4 + (threadIdx.x >> 6);
  int lane = threadIdx.x & 63;
  if (n >= N) return;
  int beg = row_ptr[n], end = row_ptr[n + 1];
  int hw = lane >> 5, sl = lane & 31;
  float2 acc = make_float2(0.f, 0.f);
  int p = beg;
  for (; p + 16 <= end; p += 16) {
    uint r[8];
    #pragma unroll
    for (int j = 0; j < 8; ++j) r[j] = edges[p + 2 * j + hw];
    uint v[8];
    #pragma unroll
    for (int j = 0; j < 8; ++j) v[j] = hb[(size_t)(r[j] & 0x1ffffu) * 32 + sl];
    #pragma unroll
    for (int j = 0; j < 8; ++j) {
      float c = __uint_as_float((r[j] >> 17) << 16);
      acc.x = fmaf(blo(v[j]), c, acc.x);
      acc.y = fmaf(bhi(v[j]), c, acc.y);
    }
  }
  for (; p < end; p += 2) {
    int pp = p + hw;
    if (pp < end) {
      uint r = edges[pp];
      uint v = hb[(size_t)(r & 0x1ffffu) * 32 + sl];
      float c = __uint_as_float((r >> 17) << 16);
      acc.x = fmaf(blo(v), c, acc.x);
      acc.y = fmaf(bhi(v), c, acc.y);
    }
  }
  acc.x += __shfl_xor(acc.x, 32, 64);
  acc.y += __shfl_xor(acc.y, 32, 64);

  float dn = dis[n];
  uint hv = hb[(size_t)n * 32 + sl];
  float2 b = reinterpret_cast<const float2*>(bias)[sl];
  acc.x = fmaf(dn * dn, blo(hv), acc.x) + b.x;
  acc.y = fmaf(dn * dn, bhi(hv), acc.y) + b.y;

  float m = fmaxf(acc.x, acc.y);
  #pragma unroll
  for (int d = 16; d; d >>= 1) m = fmaxf(m, __shfl_xor(m, d, 64));
  float e = __expf(acc.x - m) + __expf(acc.y - m);
  #pragma unroll
  for (int d = 16; d; d >>= 1) e += __shfl_xor(e, d, 64);
  float lse = m + __logf(e);
  acc.x -= lse;
  acc.y -= lse;
  if (hw == 0)
    reinterpret_cast<float2*>(out + (size_t)n * 64)[sl] = acc;
}

extern "C" void kernel_launch(void* const* d_in, const int* in_sizes, int n_in,
                              void* d_out, int out_size, void* d_ws, size_t ws_size,
                              hipStream_t stream) {
  const float* x  = (const float*)d_in[0];
  const int*   ei = (const int*)d_in[1];
  const float* W0 = (const float*)d_in[2];
  const float* b0 = (const float*)d_in[3];
  const float* W1 = (const float*)d_in[4];
  const float* b1 = (const float*)d_in[5];
  const float* W2 = (const float*)d_in[6];
  const float* b2 = (const float*)d_in[7];
  float* out = (float*)d_out;

  const int N = NN, E = NE;
  const int* src = ei;
  const int* dst = ei + E;

  char* ws = (char*)d_ws;
  size_t off = 0;
  auto alloc = [&](size_t bytes) -> void* {
    off = (off + 255) & ~(size_t)255;
    void* p = ws + off;
    off += bytes;
    return p;
  };
  uint*   cnt     = (uint*)alloc((size_t)N * 4);
  float*  dis     = (float*)alloc((size_t)N * 4);
  int*    row_ptr = (int*)alloc((size_t)(N + 1) * 4);
  int*    gcur    = (int*)alloc((size_t)NCB * 4);
  uint*   ebuf    = (uint*)alloc((size_t)NCB * CAP * 4);
  uint*   edges   = (uint*)alloc((size_t)E * 4);
  uint*   bsum    = (uint*)alloc(128 * 4);
  uint*   boff    = (uint*)alloc(128 * 4);
  ushort* bufAb   = (ushort*)alloc((size_t)N * 128 * 2);  // gemm bf16 out
  ushort* bufBb   = (ushort*)alloc((size_t)N * 128 * 2);  // agg bf16 out / gemm in

  const int nb = (N + 1023) / 1024;  // 98

  // ---- CSR build ----
  k_init<<<(N + 255) / 256, 256, 0, stream>>>(cnt, gcur);
  k_binA<<<SC_BLOCKS, 256, 0, stream>>>(src, dst, cnt, gcur, ebuf, E);
  k_scan1<<<nb, 1024, 0, stream>>>(cnt, bsum, dis, N);
  k_scan2<<<1, 128, 0, stream>>>(bsum, boff, nb, row_ptr, N, E);
  k_scan3<<<nb, 1024, 0, stream>>>(cnt, boff, row_ptr, N);
  k_sortB<<<NCB, 512, 0, stream>>>(ebuf, gcur, row_ptr, dis, edges, N);

  const int gemm_grid = (N + 63) / 64;   // 1563
  const int node_grid = (N + 3) / 4;     // 25000

  // ---- layer 0 ----
  k_gemm<128, false><<<gemm_grid, 256, 0, stream>>>(x, W0, bufAb, N);
  k_agg128<<<node_grid, 256, 0, stream>>>((const uint*)bufAb, row_ptr, edges, dis, b0, (uint*)bufBb, N);
  // ---- layer 1 ----
  k_gemm<128, true><<<gemm_grid, 256, 0, stream>>>(bufBb, W1, bufAb, N);
  k_agg128<<<node_grid, 256, 0, stream>>>((const uint*)bufAb, row_ptr, edges, dis, b1, (uint*)bufBb, N);
  // ---- layer 2 (fused log_softmax epilogue) ----
  k_gemm<64, true><<<gemm_grid, 256, 0, stream>>>(bufBb, W2, bufAb, N);
  k_agg64<<<node_grid, 256, 0, stream>>>((const uint*)bufAb, row_ptr, edges, dis, b2, out, N);
}